// Round 2
// baseline (279.486 us; speedup 1.0000x reference)
//
#include <hip/hip_runtime.h>
#include <stdint.h>

// B=2, CIN=256, COUT=256, H=W=128, K=3, G=4
#define HW    16384
#define CIN   256
#define COUT  256
#define Hh    128
#define Ww    128
#define OFFC  72        // G*2*K*K

typedef __attribute__((ext_vector_type(4))) float    f32x4;
typedef __attribute__((ext_vector_type(2))) _Float16 f16x2;
typedef __attribute__((ext_vector_type(8))) _Float16 f16x8;
typedef unsigned short u16;
typedef unsigned int   u32;

__device__ __forceinline__ u16 f2h(float f) { return __builtin_bit_cast(u16, (_Float16)f); }
__device__ __forceinline__ u32 pk2(float f) { u32 h = f2h(f); return h | (h << 16); }
__device__ __forceinline__ f16x2 bch(u32 u) { return __builtin_bit_cast(f16x2, u); }

// ---------------------------------------------------------------------------
// KPREP: unchanged from R1 (coalesced xt store).
// ---------------------------------------------------------------------------
__global__ __launch_bounds__(256) void kprep(const float* __restrict__ x, const float* __restrict__ wd,
                                             const float* __restrict__ wo, u16* __restrict__ xt,
                                             u16* __restrict__ wfrag, u16* __restrict__ wfrag2) {
  __shared__ float smem[64 * 129];              // 33 KB
  int blk = blockIdx.x;
  if (blk < 1024) {                             // ---- transpose to NHWC f16, 128 px ----
    int bg = blk >> 7;
    int p0 = (blk & 127) << 7;
    const float* src = x + (size_t)bg * 64 * HW + p0;
    #pragma unroll
    for (int r = 0; r < 8; ++r) {
      int idx = (threadIdx.x + 256 * r) * 4;    // 0..8191
      int c = idx >> 7, px = idx & 127;
      f32x4 v = *(const f32x4*)(src + (size_t)c * HW + px);
      smem[c * 129 + px + 0] = v[0];
      smem[c * 129 + px + 1] = v[1];
      smem[c * 129 + px + 2] = v[2];
      smem[c * 129 + px + 3] = v[3];
    }
    __syncthreads();
    u16* dstb = xt + ((size_t)bg * HW + p0) * 64;
    #pragma unroll
    for (int k = 0; k < 4; ++k) {
      int e  = k * 256 + threadIdx.x;           // 0..1023
      int px = e >> 3, ck = e & 7;
      u32 w[4];
      #pragma unroll
      for (int m = 0; m < 4; ++m) {
        float lo = smem[(ck * 8 + 2 * m + 0) * 129 + px];
        float hi = smem[(ck * 8 + 2 * m + 1) * 129 + px];
        w[m] = (u32)f2h(lo) | ((u32)f2h(hi) << 16);
      }
      *(uint4*)(dstb + (size_t)e * 8) = make_uint4(w[0], w[1], w[2], w[3]);
    }
  } else if (blk < 1152) {                      // ---- w_deform prepack (8 couts) ----
    int bb = blk - 1024;                        // 0..127
    int nh = bb & 31;                           // couts [nh*8, nh*8+8)
    int g  = bb >> 5;
    const float* src = wd + (size_t)(nh * 8) * 2304 + (size_t)g * 64 * 9;
    #pragma unroll
    for (int r = 0; r < 18; ++r) {
      int idx = threadIdx.x + 256 * r;          // 0..4607
      int cl  = idx / 576;
      int rem = idx - cl * 576;
      smem[cl * 576 + rem] = src[(size_t)cl * 2304 + rem];
    }
    __syncthreads();
    int nt = nh >> 1, nb = (nh & 1) * 8;
    #pragma unroll
    for (int r = 0; r < 18; ++r) {
      int o  = threadIdx.x + 256 * r;           // 0..4607
      int j  = o & 7;
      int n8 = (o >> 3) & 7;
      int q  = (o >> 6) & 3;
      int kcl = o >> 8;                         // t*2+half
      int t = kcl >> 1, half = kcl & 1;
      int cg = half * 32 + q * 8 + j;
      float v = smem[n8 * 576 + cg * 9 + t];
      int kc = (g * 9 + t) * 2 + half;
      int lane = q * 16 + nb + n8;
      wfrag[((size_t)(kc * 16 + nt) * 64 + lane) * 8 + j] = f2h(v);
    }
  } else {                                      // ---- w_offset prepack ----
    int e = (blk - 1152) * 256 + threadIdx.x;   // < 20480
    int j = e & 7;
    int lane = (e >> 3) & 63;
    int idx = e >> 9;
    int kc = idx / 5, nt = idx - 5 * kc;
    int n16 = lane & 15, q = lane >> 4;
    int oc = nt * 16 + n16;
    int c  = kc * 32 + q * 8 + j;
    float v = (oc < OFFC) ? wo[(size_t)oc * CIN + c] : 0.f;
    wfrag2[e] = f2h(v);
  }
}

// ---------------------------------------------------------------------------
// K2 (R10): barrier-free main loop. Block = 8 waves, 64 px, 256 cout.
//   Wave wv: px-subtile sp = wv&3, cout-half ch = wv>>2 (128 couts).
//   Each wave gathers + bilerps its OWN 16px x 64ch A-data per tap; the bilerp
//   output registers ARE the MFMA A-fragments (lane n16+16q holds px n16,
//   ch-chunk q of half h) -- no LDS staging, no astage, no main-loop barriers.
//   B (wfrag) read per-tap from L2/L1; the 4 sp-waves of a ch-half issue
//   identical B addresses in the same order (L1 reuse).
//   Only sync: one __syncthreads after the offset-conv phase fills offl.
// ---------------------------------------------------------------------------
__device__ __forceinline__ void mkpre(float yy, float xx, int* ob, u32* wp) {
  float y0f = floorf(yy), x0f = floorf(xx);
  float fy = yy - y0f, fx = xx - x0f;
  int y0 = (int)y0f, x0 = (int)x0f;
  int y1 = y0 + 1, x1 = x0 + 1;
  float vy0 = (y0 >= 0 && y0 < Hh) ? 1.f : 0.f;
  float vy1 = (y1 >= 0 && y1 < Hh) ? 1.f : 0.f;
  float vx0 = (x0 >= 0 && x0 < Ww) ? 1.f : 0.f;
  float vx1 = (x1 >= 0 && x1 < Ww) ? 1.f : 0.f;
  wp[0] = pk2((1.f - fy) * (1.f - fx) * vy0 * vx0);   // zero-pad folded into weights
  wp[1] = pk2((1.f - fy) * fx * vy0 * vx1);
  wp[2] = pk2(fy * (1.f - fx) * vy1 * vx0);
  wp[3] = pk2(fy * fx * vy1 * vx1);
  int cy0 = min(max(y0, 0), Hh - 1), cy1 = min(max(y1, 0), Hh - 1);
  int cx0 = min(max(x0, 0), Ww - 1), cx1 = min(max(x1, 0), Ww - 1);
  ob[0] = (cy0 * Ww + cx0) << 7;                // byte offsets, 128 B pixel records
  ob[1] = (cy0 * Ww + cx1) << 7;
  ob[2] = (cy1 * Ww + cx0) << 7;
  ob[3] = (cy1 * Ww + cx1) << 7;
}

__device__ __forceinline__ f16x8 bil16(const uint4* v, const u32* wp) {
  f16x2 W0 = bch(wp[0]), W1 = bch(wp[1]), W2 = bch(wp[2]), W3 = bch(wp[3]);
  uint4 r;
  { f16x2 s = bch(v[0].x) * W0 + bch(v[1].x) * W1 + bch(v[2].x) * W2 + bch(v[3].x) * W3; r.x = __builtin_bit_cast(u32, s); }
  { f16x2 s = bch(v[0].y) * W0 + bch(v[1].y) * W1 + bch(v[2].y) * W2 + bch(v[3].y) * W3; r.y = __builtin_bit_cast(u32, s); }
  { f16x2 s = bch(v[0].z) * W0 + bch(v[1].z) * W1 + bch(v[2].z) * W2 + bch(v[3].z) * W3; r.z = __builtin_bit_cast(u32, s); }
  { f16x2 s = bch(v[0].w) * W0 + bch(v[1].w) * W1 + bch(v[2].w) * W2 + bch(v[3].w) * W3; r.w = __builtin_bit_cast(u32, s); }
  return __builtin_bit_cast(f16x8, r);
}

__global__ __launch_bounds__(512, 4) void k2(const u16* __restrict__ xt, const u16* __restrict__ wfrag2,
                                             const float* __restrict__ bo, const u16* __restrict__ wfrag,
                                             float* __restrict__ out) {
  __shared__ float offl[64 * 74];               // [px][oc] stride-74, 18.9 KB (only LDS)
  int tid  = threadIdx.x;
  int lane = tid & 63, n16 = lane & 15, q = (tid >> 4) & 3;
  int wv   = tid >> 6;                          // 0..7
  int sp   = wv & 3;                            // px subtile (16 px)
  int ch   = wv >> 2;                           // cout half (128 couts)
  int b  = blockIdx.x >> 8;
  int p0 = (blockIdx.x & 255) << 6;
  int h  = p0 >> 7, w0 = p0 & 127;
  const char* xtb = (const char*)xt + (size_t)b * 4 * HW * 128;
  float fh  = (float)h;
  float fxp = (float)(w0 + sp * 16 + n16);      // this lane's pixel x
  int   q16 = q * 16;                           // ch-chunk byte offset within 64B half

  f32x4 acc[8];
  #pragma unroll
  for (int nt = 0; nt < 8; ++nt) acc[nt] = (f32x4){0.f, 0.f, 0.f, 0.f};

  // ---- phase 0: waves 0-3 (ch==0, sp==wv) compute offset conv -> offl ----
  if (wv < 4) {
    f32x4 oacc[5];
    #pragma unroll
    for (int nt = 0; nt < 5; ++nt) {
      int oc = nt * 16 + n16;
      float bv = (oc < OFFC) ? bo[oc] : 0.f;
      oacc[nt] = (f32x4){bv, bv, bv, bv};
    }
    #pragma unroll
    for (int kc = 0; kc < 8; ++kc) {
      int g = kc >> 1;
      f16x8 af = __builtin_bit_cast(f16x8, *(const uint4*)(xtb +
          ((size_t)(g * HW + p0 + wv * 16 + n16)) * 128 + (kc & 1) * 64 + q * 16));
      #pragma unroll
      for (int nt = 0; nt < 5; ++nt) {
        f16x8 bfo = __builtin_bit_cast(f16x8, *(const uint4*)(wfrag2 + (size_t)(((kc * 5 + nt) << 6) + lane) * 8));
        oacc[nt] = __builtin_amdgcn_mfma_f32_16x16x32_f16(af, bfo, oacc[nt], 0, 0, 0);
      }
    }
    #pragma unroll
    for (int nt = 0; nt < 5; ++nt) {
      int oc = nt * 16 + n16;
      if (oc < OFFC) {
        #pragma unroll
        for (int r = 0; r < 4; ++r)
          offl[(wv * 16 + q * 4 + r) * 74 + oc] = oacc[nt][r];
      }
    }
  }
  __syncthreads();                              // offl ready; last barrier in kernel

  int   pxl = sp * 16 + n16;
  int   ob[4];
  u32   wpA[4], wpB[4];                         // ping-pong bilerp weights
  uint4 d0[4], d1[4];                           // corner data, half0 / half1

  auto prep = [&](int gt, u32* wp) {            // offsets + addresses for tap gt
    float oy = offl[pxl * 74 + gt * 2];
    float ox = offl[pxl * 74 + gt * 2 + 1];
    int g = (gt * 57) >> 9;                     // gt/9
    int t = gt - g * 9;
    int i = (t * 683) >> 11;                    // t/3
    int j = t - i * 3;
    mkpre(fh + (float)(i - 1) + oy, fxp + (float)(j - 1) + ox, ob, wp);
    int gb = g * (HW * 128) + q16;
    #pragma unroll
    for (int c = 0; c < 4; ++c) ob[c] += gb;
  };
  auto gload = [&]() {                          // issue 8 corner gathers (both halves)
    #pragma unroll
    for (int c = 0; c < 4; ++c) {
      d0[c] = *(const uint4*)(xtb + ob[c]);
      d1[c] = *(const uint4*)(xtb + ob[c] + 64);
    }
  };
  auto mm = [&](int gt, f16x8 a0, f16x8 a1) {   // 16 MFMA for tap gt
    const u16* wb = wfrag + ((size_t)((gt * 2) * 16 + ch * 8) * 64 + lane) * 8;
    #pragma unroll
    for (int nt = 0; nt < 8; ++nt) {
      f16x8 b0 = __builtin_bit_cast(f16x8, *(const uint4*)(wb + nt * 512));
      f16x8 b1 = __builtin_bit_cast(f16x8, *(const uint4*)(wb + 8192 + nt * 512));
      acc[nt] = __builtin_amdgcn_mfma_f32_16x16x32_f16(a0, b0, acc[nt], 0, 0, 0);
      acc[nt] = __builtin_amdgcn_mfma_f32_16x16x32_f16(a1, b1, acc[nt], 0, 0, 0);
    }
  };

  // ---- barrier-free main loop, x2 unrolled, 1-tap gather prefetch ----
  prep(0, wpA); gload();
  #pragma unroll 1
  for (int gt = 0; gt < 36; gt += 2) {
    f16x8 a0 = bil16(d0, wpA);                  // waits on d (tap gt)
    f16x8 a1 = bil16(d1, wpA);
    prep(gt + 1, wpB); gload();                 // tap gt+1 in flight under MFMAs
    mm(gt, a0, a1);
    a0 = bil16(d0, wpB);
    a1 = bil16(d1, wpB);
    if (gt + 2 < 36) { prep(gt + 2, wpA); gload(); }
    mm(gt + 1, a0, a1);
  }

  // ---- epilogue: px = p0 + sp*16 + q*4 + r, cout = ch*128 + nt*16 + n16 ----
  float* op = out + (size_t)b * COUT * HW + p0 + sp * 16;
  #pragma unroll
  for (int nt = 0; nt < 8; ++nt) {
    f32x4 v = acc[nt];
    #pragma unroll
    for (int r = 0; r < 4; ++r) v[r] = fmaxf(v[r], 0.f);
    int cout = ch * 128 + nt * 16 + n16;
    *(f32x4*)(op + (size_t)cout * HW + q * 4) = v;
  }
}

// ---------------------------------------------------------------------------
extern "C" void kernel_launch(void* const* d_in, const int* in_sizes, int n_in,
                              void* d_out, int out_size, void* d_ws, size_t ws_size,
                              hipStream_t stream) {
  const float* x  = (const float*)d_in[0];
  const float* wo = (const float*)d_in[1];
  const float* bo = (const float*)d_in[2];
  const float* wd = (const float*)d_in[3];
  float* out = (float*)d_out;

  // ws: xt 16,777,216 | wfrag 1,179,648 | wfrag2 40,960
  u16* xtp    = (u16*)d_ws;
  u16* wfrag  = (u16*)((char*)d_ws + 16777216);
  u16* wfrag2 = (u16*)((char*)d_ws + 16777216 + 1179648);

  kprep<<<1232, 256, 0, stream>>>(x, wd, wo, xtp, wfrag, wfrag2);
  k2   <<<512,  512, 0, stream>>>(xtp, wfrag2, bo, wfrag, out);
}

// Round 3
// 192.414 us; speedup vs baseline: 1.4525x; 1.4525x over previous
//
#include <hip/hip_runtime.h>
#include <stdint.h>

// B=2, CIN=256, COUT=256, H=W=128, K=3, G=4
#define HW    16384
#define CIN   256
#define COUT  256
#define Hh    128
#define Ww    128
#define OFFC  72        // G*2*K*K

typedef __attribute__((ext_vector_type(4))) float    f32x4;
typedef __attribute__((ext_vector_type(2))) _Float16 f16x2;
typedef __attribute__((ext_vector_type(8))) _Float16 f16x8;
typedef unsigned short u16;
typedef unsigned int   u32;

__device__ __forceinline__ u16 f2h(float f) { return __builtin_bit_cast(u16, (_Float16)f); }
__device__ __forceinline__ u32 pk2(float f) { u32 h = f2h(f); return h | (h << 16); }
__device__ __forceinline__ f16x2 bch(u32 u) { return __builtin_bit_cast(f16x2, u); }

// lgkmcnt-only barrier: LDS ops retired, global gathers stay in flight.
// Minimal form (no sched_barrier pins, no setprio -- R1 confounders removed).
// Empty asm after the barrier pins compiler-level memory-op ordering.
__device__ __forceinline__ void bar() {
  asm volatile("s_waitcnt lgkmcnt(0)" ::: "memory");
  __builtin_amdgcn_s_barrier();
  asm volatile("" ::: "memory");
}

// ---------------------------------------------------------------------------
// KPREP: unchanged (coalesced xt store version).
// ---------------------------------------------------------------------------
__global__ __launch_bounds__(256) void kprep(const float* __restrict__ x, const float* __restrict__ wd,
                                             const float* __restrict__ wo, u16* __restrict__ xt,
                                             u16* __restrict__ wfrag, u16* __restrict__ wfrag2) {
  __shared__ float smem[64 * 129];              // 33 KB
  int blk = blockIdx.x;
  if (blk < 1024) {                             // ---- transpose to NHWC f16, 128 px ----
    int bg = blk >> 7;
    int p0 = (blk & 127) << 7;
    const float* src = x + (size_t)bg * 64 * HW + p0;
    #pragma unroll
    for (int r = 0; r < 8; ++r) {
      int idx = (threadIdx.x + 256 * r) * 4;    // 0..8191
      int c = idx >> 7, px = idx & 127;
      f32x4 v = *(const f32x4*)(src + (size_t)c * HW + px);
      smem[c * 129 + px + 0] = v[0];
      smem[c * 129 + px + 1] = v[1];
      smem[c * 129 + px + 2] = v[2];
      smem[c * 129 + px + 3] = v[3];
    }
    __syncthreads();
    u16* dstb = xt + ((size_t)bg * HW + p0) * 64;
    #pragma unroll
    for (int k = 0; k < 4; ++k) {
      int e  = k * 256 + threadIdx.x;           // 0..1023
      int px = e >> 3, ck = e & 7;
      u32 w[4];
      #pragma unroll
      for (int m = 0; m < 4; ++m) {
        float lo = smem[(ck * 8 + 2 * m + 0) * 129 + px];
        float hi = smem[(ck * 8 + 2 * m + 1) * 129 + px];
        w[m] = (u32)f2h(lo) | ((u32)f2h(hi) << 16);
      }
      *(uint4*)(dstb + (size_t)e * 8) = make_uint4(w[0], w[1], w[2], w[3]);
    }
  } else if (blk < 1152) {                      // ---- w_deform prepack (8 couts) ----
    int bb = blk - 1024;                        // 0..127
    int nh = bb & 31;                           // couts [nh*8, nh*8+8)
    int g  = bb >> 5;
    const float* src = wd + (size_t)(nh * 8) * 2304 + (size_t)g * 64 * 9;
    #pragma unroll
    for (int r = 0; r < 18; ++r) {
      int idx = threadIdx.x + 256 * r;          // 0..4607
      int cl  = idx / 576;
      int rem = idx - cl * 576;
      smem[cl * 576 + rem] = src[(size_t)cl * 2304 + rem];
    }
    __syncthreads();
    int nt = nh >> 1, nb = (nh & 1) * 8;
    #pragma unroll
    for (int r = 0; r < 18; ++r) {
      int o  = threadIdx.x + 256 * r;           // 0..4607
      int j  = o & 7;
      int n8 = (o >> 3) & 7;
      int q  = (o >> 6) & 3;
      int kcl = o >> 8;                         // t*2+half
      int t = kcl >> 1, half = kcl & 1;
      int cg = half * 32 + q * 8 + j;
      float v = smem[n8 * 576 + cg * 9 + t];
      int kc = (g * 9 + t) * 2 + half;
      int lane = q * 16 + nb + n8;
      wfrag[((size_t)(kc * 16 + nt) * 64 + lane) * 8 + j] = f2h(v);
    }
  } else {                                      // ---- w_offset prepack ----
    int e = (blk - 1152) * 256 + threadIdx.x;   // < 20480
    int j = e & 7;
    int lane = (e >> 3) & 63;
    int idx = e >> 9;
    int kc = idx / 5, nt = idx - 5 * kc;
    int n16 = lane & 15, q = lane >> 4;
    int oc = nt * 16 + n16;
    int c  = kc * 32 + q * 8 + j;
    float v = (oc < OFFC) ? wo[(size_t)oc * CIN + c] : 0.f;
    wfrag2[e] = f2h(v);
  }
}

// ---------------------------------------------------------------------------
// K2 (R11): R0 dataflow shrunk to 4-wave blocks for 4 barrier domains / CU.
//   Block = 256 thr (4 waves), 32 px x 256 cout. Grid 1024 = 4 blocks/CU.
//   Wave w: PRODUCES half-tile (sp=w&1 px-subtile, hp=w>>1 ch-half): 4 corner
//   gathers + bilerp -> LDS. CONSUMES 4 half-tiles x couts [w*64,(w+1)*64):
//   acc[2][4] = 32 regs, 16 MFMA/tap. One lgkmcnt-only barrier per tap;
//   gathers for tap t+1 issued before consume(t) -> a full consume in flight.
//   XCD-bijective blockIdx swizzle: each XCD works a contiguous 32-row slice
//   of the image -> its xt gather set (~2 MB + halo) fits the 4 MB XCD L2.
// ---------------------------------------------------------------------------
__device__ __forceinline__ void mkpre(float yy, float xx, int* ob, u32* wp) {
  float y0f = floorf(yy), x0f = floorf(xx);
  float fy = yy - y0f, fx = xx - x0f;
  int y0 = (int)y0f, x0 = (int)x0f;
  int y1 = y0 + 1, x1 = x0 + 1;
  float vy0 = (y0 >= 0 && y0 < Hh) ? 1.f : 0.f;
  float vy1 = (y1 >= 0 && y1 < Hh) ? 1.f : 0.f;
  float vx0 = (x0 >= 0 && x0 < Ww) ? 1.f : 0.f;
  float vx1 = (x1 >= 0 && x1 < Ww) ? 1.f : 0.f;
  wp[0] = pk2((1.f - fy) * (1.f - fx) * vy0 * vx0);   // zero-pad folded into weights
  wp[1] = pk2((1.f - fy) * fx * vy0 * vx1);
  wp[2] = pk2(fy * (1.f - fx) * vy1 * vx0);
  wp[3] = pk2(fy * fx * vy1 * vx1);
  int cy0 = min(max(y0, 0), Hh - 1), cy1 = min(max(y1, 0), Hh - 1);
  int cx0 = min(max(x0, 0), Ww - 1), cx1 = min(max(x1, 0), Ww - 1);
  ob[0] = (cy0 * Ww + cx0) << 7;                // byte offsets, 128 B pixel records
  ob[1] = (cy0 * Ww + cx1) << 7;
  ob[2] = (cy1 * Ww + cx0) << 7;
  ob[3] = (cy1 * Ww + cx1) << 7;
}

__device__ __forceinline__ uint4 bil16(const uint4* v, const u32* wp) {
  f16x2 W0 = bch(wp[0]), W1 = bch(wp[1]), W2 = bch(wp[2]), W3 = bch(wp[3]);
  uint4 r;
  { f16x2 s = bch(v[0].x) * W0 + bch(v[1].x) * W1 + bch(v[2].x) * W2 + bch(v[3].x) * W3; r.x = __builtin_bit_cast(u32, s); }
  { f16x2 s = bch(v[0].y) * W0 + bch(v[1].y) * W1 + bch(v[2].y) * W2 + bch(v[3].y) * W3; r.y = __builtin_bit_cast(u32, s); }
  { f16x2 s = bch(v[0].z) * W0 + bch(v[1].z) * W1 + bch(v[2].z) * W2 + bch(v[3].z) * W3; r.z = __builtin_bit_cast(u32, s); }
  { f16x2 s = bch(v[0].w) * W0 + bch(v[1].w) * W1 + bch(v[2].w) * W2 + bch(v[3].w) * W3; r.w = __builtin_bit_cast(u32, s); }
  return r;
}

__global__ __launch_bounds__(256, 4) void k2(const u16* __restrict__ xt, const u16* __restrict__ wfrag2,
                                             const float* __restrict__ bo, const u16* __restrict__ wfrag,
                                             float* __restrict__ out) {
  __shared__ u16   astage[2 * 4 * 512];         // [buf][sp2*hp2][lane][8] = 8 KB
  __shared__ float offl[32 * 74];               // [px][oc] stride-74, 9.25 KB
  int tid  = threadIdx.x;
  int lane = tid & 63, n16 = lane & 15, q = (tid >> 4) & 3;
  int wv   = tid >> 6;                          // 0..3
  int sp   = wv & 1;                            // produced px subtile
  int hp   = wv >> 1;                           // produced 32-ch half
  int blk  = blockIdx.x;
  int swz  = (blk & 7) * 128 + (blk >> 3);      // bijective XCD swizzle (1024%8==0)
  int b  = swz >> 9;
  int p0 = (swz & 511) << 5;                    // 32-px tile
  int h  = p0 >> 7, w0 = p0 & 127;
  const char* xtb = (const char*)xt + (size_t)b * 4 * HW * 128;
  float fh  = (float)h;
  float fxp = (float)(w0 + sp * 16 + n16);      // producer-pixel x
  int   chb = hp * 64 + q * 16;                 // byte offset within 128 B record
  int   pxl = sp * 16 + n16;

  f32x4 acc[2][4];
  #pragma unroll
  for (int mt = 0; mt < 2; ++mt)
    #pragma unroll
    for (int i = 0; i < 4; ++i) acc[mt][i] = (f32x4){0.f, 0.f, 0.f, 0.f};

  // ---- phase 0: waves 0-1 compute offset conv (32 px x 72 oc) -> offl ----
  if (wv < 2) {
    f32x4 oacc[5];
    #pragma unroll
    for (int nt = 0; nt < 5; ++nt) {
      int oc = nt * 16 + n16;
      float bv = (oc < OFFC) ? bo[oc] : 0.f;
      oacc[nt] = (f32x4){bv, bv, bv, bv};
    }
    #pragma unroll
    for (int kc = 0; kc < 8; ++kc) {
      int g = kc >> 1;
      f16x8 af = __builtin_bit_cast(f16x8, *(const uint4*)(xtb +
          ((size_t)(g * HW + p0 + wv * 16 + n16)) * 128 + (kc & 1) * 64 + q * 16));
      #pragma unroll
      for (int nt = 0; nt < 5; ++nt) {
        f16x8 bfo = __builtin_bit_cast(f16x8, *(const uint4*)(wfrag2 + (size_t)(((kc * 5 + nt) << 6) + lane) * 8));
        oacc[nt] = __builtin_amdgcn_mfma_f32_16x16x32_f16(af, bfo, oacc[nt], 0, 0, 0);
      }
    }
    #pragma unroll
    for (int nt = 0; nt < 5; ++nt) {
      int oc = nt * 16 + n16;
      if (oc < OFFC) {
        #pragma unroll
        for (int r = 0; r < 4; ++r)
          offl[(wv * 16 + q * 4 + r) * 74 + oc] = oacc[nt][r];
      }
    }
  }
  uint4 bf0[4];                                 // persistent hh=0 B-frags (nt = 4wv+i)
  #pragma unroll
  for (int i = 0; i < 4; ++i)
    bf0[i] = *(const uint4*)(wfrag + ((size_t)(4 * wv + i) * 64 + lane) * 8);
  __syncthreads();                              // offl ready (full drain, one-time)

  uint4 d[4];                                   // in-flight corner gathers (const-indexed)
  u32   wp[4];

  auto pg = [&](int gt) {                       // prep offsets + issue 4 gathers for tap gt
    float oy = offl[pxl * 74 + gt * 2];
    float ox = offl[pxl * 74 + gt * 2 + 1];
    int g = (gt * 57) >> 9;                     // gt/9
    int t = gt - g * 9;
    int i = (t * 683) >> 11;                    // t/3
    int j = t - i * 3;
    int ob[4];
    mkpre(fh + (float)(i - 1) + oy, fxp + (float)(j - 1) + ox, ob, wp);
    const char* xg = xtb + (size_t)g * HW * 128;
    #pragma unroll
    for (int c = 0; c < 4; ++c)
      d[c] = *(const uint4*)(xg + ob[c] + chb);
  };
  auto consume = [&](int slot, int gt) {        // slot is a literal at each call site
    uint4 bf1[4];
    const u16* wb1 = wfrag + ((size_t)((2 * gt + 1) * 16 + 4 * wv) * 64 + lane) * 8;
    #pragma unroll
    for (int i = 0; i < 4; ++i) bf1[i] = *(const uint4*)(wb1 + i * 512);
    #pragma unroll
    for (int mt = 0; mt < 2; ++mt) {
      f16x8 af = __builtin_bit_cast(f16x8,
          *(const uint4*)&astage[(slot * 4 + mt * 2 + 0) * 512 + lane * 8]);
      #pragma unroll
      for (int i = 0; i < 4; ++i)
        acc[mt][i] = __builtin_amdgcn_mfma_f32_16x16x32_f16(af, __builtin_bit_cast(f16x8, bf0[i]), acc[mt][i], 0, 0, 0);
    }
    #pragma unroll
    for (int mt = 0; mt < 2; ++mt) {
      f16x8 af = __builtin_bit_cast(f16x8,
          *(const uint4*)&astage[(slot * 4 + mt * 2 + 1) * 512 + lane * 8]);
      #pragma unroll
      for (int i = 0; i < 4; ++i)
        acc[mt][i] = __builtin_amdgcn_mfma_f32_16x16x32_f16(af, __builtin_bit_cast(f16x8, bf1[i]), acc[mt][i], 0, 0, 0);
    }
    if (gt < 35) {                              // prefetch hh=0 B of tap gt+1
      const u16* wb0 = wfrag + ((size_t)((2 * gt + 2) * 16 + 4 * wv) * 64 + lane) * 8;
      #pragma unroll
      for (int i = 0; i < 4; ++i) bf0[i] = *(const uint4*)(wb0 + i * 512);
    }
  };

  // ---- prologue: gather tap0; phase 0 stages tap0 -> slot0, issues tap1 ----
  pg(0);
  *(uint4*)&astage[(0 * 4 + sp * 2 + hp) * 512 + lane * 8] = bil16(d, wp);
  pg(1);
  bar();                                        // slot0 ready; tap1 gathers in flight

  // ---- main loop: phase per tap, x2 unrolled for slot parity ----
  #pragma unroll 1
  for (int t = 0; t < 36; t += 2) {
    // phase t+1: stage tap t+1 -> slot1; issue tap t+2; consume tap t (slot0)
    *(uint4*)&astage[(1 * 4 + sp * 2 + hp) * 512 + lane * 8] = bil16(d, wp);
    if (t + 2 < 36) pg(t + 2);
    consume(0, t);
    bar();
    // phase t+2: stage tap t+2 -> slot0; issue tap t+3; consume tap t+1 (slot1)
    if (t + 2 < 36) {
      *(uint4*)&astage[(0 * 4 + sp * 2 + hp) * 512 + lane * 8] = bil16(d, wp);
      if (t + 3 < 36) pg(t + 3);
    }
    consume(1, t + 1);
    bar();
  }

  // ---- epilogue: px = p0 + mt*16 + q*4 + r, cout = wv*64 + i*16 + n16; ReLU ----
  float* op = out + (size_t)b * COUT * HW + p0;
  #pragma unroll
  for (int mt = 0; mt < 2; ++mt)
    #pragma unroll
    for (int i = 0; i < 4; ++i) {
      f32x4 v = acc[mt][i];
      #pragma unroll
      for (int r = 0; r < 4; ++r) v[r] = fmaxf(v[r], 0.f);
      int cout = wv * 64 + i * 16 + n16;
      *(f32x4*)(op + (size_t)cout * HW + mt * 16 + q * 4) = v;
    }
}

// ---------------------------------------------------------------------------
extern "C" void kernel_launch(void* const* d_in, const int* in_sizes, int n_in,
                              void* d_out, int out_size, void* d_ws, size_t ws_size,
                              hipStream_t stream) {
  const float* x  = (const float*)d_in[0];
  const float* wo = (const float*)d_in[1];
  const float* bo = (const float*)d_in[2];
  const float* wd = (const float*)d_in[3];
  float* out = (float*)d_out;

  // ws: xt 16,777,216 | wfrag 1,179,648 | wfrag2 40,960
  u16* xtp    = (u16*)d_ws;
  u16* wfrag  = (u16*)((char*)d_ws + 16777216);
  u16* wfrag2 = (u16*)((char*)d_ws + 16777216 + 1179648);

  kprep<<<1232, 256, 0, stream>>>(x, wd, wo, xtp, wfrag, wfrag2);
  k2   <<<1024, 256, 0, stream>>>(xtp, wfrag2, bo, wfrag, out);
}